// Round 2
// baseline (1103.763 us; speedup 1.0000x reference)
//
#include <hip/hip_runtime.h>
#include <hip/hip_bf16.h>
#include <math.h>

// Problem constants
#define BQ   16384        // windows
#define CH   512
#define NH   8
#define HID  2048
#define NTOK (BQ*4)       // 65536 rows

using bf16 = __hip_bfloat16;
typedef __bf16 bf16x8 __attribute__((ext_vector_type(8)));
typedef float  f32x4  __attribute__((ext_vector_type(4)));

#define FENCE() asm volatile("" ::: "memory")

__device__ __forceinline__ void gload16(const void* g, void* l) {
    __builtin_amdgcn_global_load_lds(
        (const __attribute__((address_space(1))) void*)g,
        (__attribute__((address_space(3))) void*)l, 16, 0, 0);
}

// ---------------- fp32 -> bf16 convert ----------------
__global__ __launch_bounds__(256) void f2b_kernel(const float* __restrict__ in,
                                                  bf16* __restrict__ out, int n) {
    int i = (blockIdx.x * 256 + threadIdx.x) * 4;
    if (i + 3 < n) {
        float4 v = *(const float4*)&in[i];
        __align__(8) bf16 t[4];
        t[0] = __float2bfloat16(v.x);
        t[1] = __float2bfloat16(v.y);
        t[2] = __float2bfloat16(v.z);
        t[3] = __float2bfloat16(v.w);
        *(uint2*)&out[i] = *(const uint2*)t;
    }
}

// ---------------- LayerNorm (fp32 in, bf16 out), one wave per row ----------------
__global__ __launch_bounds__(256) void ln_kernel(const float* __restrict__ x,
                                                 const float* __restrict__ g,
                                                 const float* __restrict__ b,
                                                 bf16* __restrict__ out) {
    int row  = blockIdx.x * 4 + (threadIdx.x >> 6);
    int lane = threadIdx.x & 63;
    const float* xr = x + (size_t)row * CH;
    int c0 = lane * 8;
    float4 v0 = *(const float4*)&xr[c0];
    float4 v1 = *(const float4*)&xr[c0 + 4];
    float s  = v0.x + v0.y + v0.z + v0.w + v1.x + v1.y + v1.z + v1.w;
    float sq = v0.x*v0.x + v0.y*v0.y + v0.z*v0.z + v0.w*v0.w
             + v1.x*v1.x + v1.y*v1.y + v1.z*v1.z + v1.w*v1.w;
#pragma unroll
    for (int off = 32; off >= 1; off >>= 1) {
        s  += __shfl_xor(s,  off, 64);
        sq += __shfl_xor(sq, off, 64);
    }
    float mu  = s * (1.0f / CH);
    float var = sq * (1.0f / CH) - mu * mu;
    float rs  = rsqrtf(var + 1e-5f);
    float4 g0 = *(const float4*)&g[c0];
    float4 g1 = *(const float4*)&g[c0 + 4];
    float4 b0 = *(const float4*)&b[c0];
    float4 b1 = *(const float4*)&b[c0 + 4];
    __align__(16) bf16 t[8];
    t[0] = __float2bfloat16((v0.x - mu) * rs * g0.x + b0.x);
    t[1] = __float2bfloat16((v0.y - mu) * rs * g0.y + b0.y);
    t[2] = __float2bfloat16((v0.z - mu) * rs * g0.z + b0.z);
    t[3] = __float2bfloat16((v0.w - mu) * rs * g0.w + b0.w);
    t[4] = __float2bfloat16((v1.x - mu) * rs * g1.x + b1.x);
    t[5] = __float2bfloat16((v1.y - mu) * rs * g1.y + b1.y);
    t[6] = __float2bfloat16((v1.z - mu) * rs * g1.z + b1.z);
    t[7] = __float2bfloat16((v1.w - mu) * rs * g1.w + b1.w);
    *(uint4*)&out[(size_t)row * CH + c0] = *(const uint4*)t;
}

// ---------------- GEMM 256x256 tile, BK=32 slices, ring-4 LDS, counted vmcnt ----
// C[M,N] = A[M,K] * B[N,K]^T
// EPI 0: outB = bf16(acc)                       (qkv)
// EPI 1: outF = acc + bias[col] + resid[idx]    (proj / fc2, fp32 out)
// EPI 2: outB = bf16(gelu(acc + bias[col]))     (fc1)
//
// LDS per slice-slot (32 KiB): A [4 kg][256 rows][16B] then B [4 kg][256 cols][16B].
// kg-outer layout: staging order (linear chunks) == layout; frag reads are
// 16 consecutive 16B rows per 16-lane group -> full bank spread (2-way, free).
// 4 slots = 128 KiB; prefetch depth 3 slices; steady-state vmcnt(12).
template<int EPI>
__global__ __launch_bounds__(512, 2)
void gemm256(const bf16* __restrict__ A, const bf16* __restrict__ Bw,
             int M, int N, int K, int nbx,
             const float* __restrict__ bias,
             const float* resid, float* outF, bf16* __restrict__ outB) {
    __shared__ __align__(16) char lds[131072];
    const int tid  = threadIdx.x;
    const int w    = tid >> 6;     // wave 0..7
    const int lane = tid & 63;

    // bijective XCD swizzle (gridDim.x % 8 == 0 for all our shapes)
    const int nb  = gridDim.x;
    const int id  = blockIdx.x;
    const int swz = (id & 7) * (nb >> 3) + (id >> 3);
    const int bx  = swz % nbx, by = swz / nbx;
    const int bm = by * 256, bn = bx * 256;
    const int wr = w >> 2;         // 0..1  (M half)
    const int wc = w & 3;          // 0..3  (N quarter)

    // staging: chunk c = w*128 + j*64 + lane ; row = c&255, kgroup = c>>8
    const int c0 = w * 128 + lane;
    const int c1 = c0 + 64;
    const bf16* ga0 = A  + (size_t)(bm + (c0 & 255)) * K + (c0 >> 8) * 8;
    const bf16* ga1 = A  + (size_t)(bm + (c1 & 255)) * K + (c1 >> 8) * 8;
    const bf16* gb0 = Bw + (size_t)(bn + (c0 & 255)) * K + (c0 >> 8) * 8;
    const bf16* gb1 = Bw + (size_t)(bn + (c1 & 255)) * K + (c1 >> 8) * 8;

    // fragment read offsets (bytes) within a slot's A / B region
    const int aoff = (lane >> 4) * 4096 + (wr * 128 + (lane & 15)) * 16;
    const int boff = (lane >> 4) * 4096 + (wc * 64  + (lane & 15)) * 16;

    f32x4 acc[8][4] = {};
    const int NS = K >> 5;         // K/32 slices (>= 16 for all our shapes)

    auto stage = [&](int ss) {
        char* base = (char*)lds + (ss & 3) * 32768;
        size_t ko = (size_t)ss * 32;
        gload16(ga0 + ko, base + w * 2048);
        gload16(ga1 + ko, base + w * 2048 + 1024);
        gload16(gb0 + ko, base + 16384 + w * 2048);
        gload16(gb1 + ko, base + 16384 + w * 2048 + 1024);
    };

    auto compute = [&](int slot) {
        const char* Ab = (const char*)lds + slot * 32768;
        const char* Bb = Ab + 16384;
        bf16x8 av[8], bv[4];
#pragma unroll
        for (int m = 0; m < 8; ++m)
            av[m] = *(const bf16x8*)(Ab + aoff + m * 256);
#pragma unroll
        for (int n = 0; n < 4; ++n)
            bv[n] = *(const bf16x8*)(Bb + boff + n * 256);
        __builtin_amdgcn_s_setprio(1);
#pragma unroll
        for (int m = 0; m < 8; ++m)
#pragma unroll
            for (int n = 0; n < 4; ++n)
                acc[m][n] = __builtin_amdgcn_mfma_f32_16x16x32_bf16(av[m], bv[n], acc[m][n], 0, 0, 0);
        __builtin_amdgcn_s_setprio(0);
    };

    stage(0); stage(1); stage(2);              // depth-3 prologue (12 loads)
    for (int s = 0; s < NS - 3; ++s) {
        stage(s + 3);                          // 16 outstanding max
        asm volatile("s_waitcnt vmcnt(12)" ::: "memory");   // slice s landed
        __builtin_amdgcn_s_barrier();
        FENCE();
        compute(s & 3);
        FENCE();
        __builtin_amdgcn_s_barrier();          // slot (s+1)&3... slot s&3 now dead
    }
    // epilogue drain: 8 -> 4 -> 0
    asm volatile("s_waitcnt vmcnt(8)" ::: "memory");
    __builtin_amdgcn_s_barrier(); FENCE();
    compute((NS - 3) & 3);
    FENCE(); __builtin_amdgcn_s_barrier();
    asm volatile("s_waitcnt vmcnt(4)" ::: "memory");
    __builtin_amdgcn_s_barrier(); FENCE();
    compute((NS - 2) & 3);
    FENCE(); __builtin_amdgcn_s_barrier();
    asm volatile("s_waitcnt vmcnt(0)" ::: "memory");
    __builtin_amdgcn_s_barrier(); FENCE();
    compute((NS - 1) & 3);

    // epilogue: frag (m,n): row = wr*128 + m*16 + (lane>>4)*4 + r, col = wc*64 + n*16 + (lane&15)
    const int erow0 = bm + wr * 128 + (lane >> 4) * 4;
    const int ecol0 = bn + wc * 64 + (lane & 15);
#pragma unroll
    for (int m = 0; m < 8; ++m) {
#pragma unroll
        for (int n = 0; n < 4; ++n) {
            int col = ecol0 + n * 16;
#pragma unroll
            for (int r = 0; r < 4; ++r) {
                int row = erow0 + m * 16 + r;
                size_t idx = (size_t)row * N + col;
                float v = acc[m][n][r];
                if (EPI == 0) {
                    outB[idx] = __float2bfloat16(v);
                } else if (EPI == 1) {
                    outF[idx] = v + bias[col] + resid[idx];
                } else {
                    float t = v + bias[col];
                    float ge = 0.5f * t * (1.0f + erff(t * 0.70710678118654752f));
                    outB[idx] = __float2bfloat16(ge);
                }
            }
        }
    }
}

// ---------------- windowed attention: one block per window ----------------
__global__ __launch_bounds__(256)
void attn_kernel(const bf16* __restrict__ qkv, const float* __restrict__ rpb,
                 bf16* __restrict__ o) {
    __shared__ __align__(16) bf16 sT[4 * 1536];
    __shared__ float sS[NH][4][4];
    __shared__ float sP[NH][4][4];
    int b   = blockIdx.x;
    int tid = threadIdx.x;
    const bf16* src = qkv + (size_t)b * (4 * 1536);
#pragma unroll
    for (int it = 0; it < 3; ++it) {
        int e = (it * 256 + tid) * 8;
        *(uint4*)&sT[e] = *(const uint4*)&src[e];
    }
    __syncthreads();
    if (tid < 128) {
        int h = tid >> 4, i = (tid >> 2) & 3, j = tid & 3;
        const bf16* q = &sT[i * 1536 + h * 64];
        const bf16* k = &sT[j * 1536 + 512 + h * 64];
        float acc = 0.f;
#pragma unroll
        for (int d = 0; d < 64; ++d)
            acc += __bfloat162float(q[d]) * __bfloat162float(k[d]);
        int rel = (((i >> 1) - (j >> 1)) + 1) * 3 + (((i & 1) - (j & 1)) + 1);
        sS[h][i][j] = acc * 0.125f + rpb[rel * NH + h];
    }
    __syncthreads();
    if (tid < 32) {
        int h = tid >> 2, i = tid & 3;
        float s0 = sS[h][i][0], s1 = sS[h][i][1], s2 = sS[h][i][2], s3 = sS[h][i][3];
        float mx = fmaxf(fmaxf(s0, s1), fmaxf(s2, s3));
        float e0 = expf(s0 - mx), e1 = expf(s1 - mx), e2 = expf(s2 - mx), e3 = expf(s3 - mx);
        float inv = 1.f / (e0 + e1 + e2 + e3);
        sP[h][i][0] = e0 * inv; sP[h][i][1] = e1 * inv;
        sP[h][i][2] = e2 * inv; sP[h][i][3] = e3 * inv;
    }
    __syncthreads();
    {
        int h = tid >> 5, tl = tid & 31;
        int d = tl * 2;
        const bf16* v = &sT[1024 + h * 64 + d];
#pragma unroll
        for (int i = 0; i < 4; ++i) {
            float p0 = sP[h][i][0], p1 = sP[h][i][1], p2 = sP[h][i][2], p3 = sP[h][i][3];
            float o0 = p0 * __bfloat162float(v[0])        + p1 * __bfloat162float(v[1536])
                     + p2 * __bfloat162float(v[2 * 1536]) + p3 * __bfloat162float(v[3 * 1536]);
            float o1 = p0 * __bfloat162float(v[1])            + p1 * __bfloat162float(v[1536 + 1])
                     + p2 * __bfloat162float(v[2 * 1536 + 1]) + p3 * __bfloat162float(v[3 * 1536 + 1]);
            __hip_bfloat162 pr;
            pr.x = __float2bfloat16(o0);
            pr.y = __float2bfloat16(o1);
            *(__hip_bfloat162*)&o[(size_t)(b * 4 + i) * CH + h * 64 + d] = pr;
        }
    }
}

extern "C" void kernel_launch(void* const* d_in, const int* in_sizes, int n_in,
                              void* d_out, int out_size, void* d_ws, size_t ws_size,
                              hipStream_t stream) {
    const float* x      = (const float*)d_in[0];
    const float* ln_g   = (const float*)d_in[1];
    const float* ln_b   = (const float*)d_in[2];
    const float* qkv_w  = (const float*)d_in[3];
    const float* proj_w = (const float*)d_in[4];
    const float* proj_b = (const float*)d_in[5];
    const float* rpb    = (const float*)d_in[6];
    const float* fc1_w  = (const float*)d_in[7];
    const float* fc1_b  = (const float*)d_in[8];
    const float* fc2_w  = (const float*)d_in[9];
    const float* fc2_b  = (const float*)d_in[10];
    float* out = (float*)d_out;

    // workspace layout (16B aligned throughout)
    char* ws = (char*)d_ws;
    bf16* wQKV  = (bf16*)ws;  ws += (size_t)1536 * 512 * 2;   // 1.5 MB
    bf16* wPROJ = (bf16*)ws;  ws += (size_t)512  * 512 * 2;   // 0.5 MB
    bf16* wFC1  = (bf16*)ws;  ws += (size_t)2048 * 512 * 2;   // 2 MB
    bf16* wFC2  = (bf16*)ws;  ws += (size_t)512 * 2048 * 2;   // 2 MB
    bf16* hA    = (bf16*)ws;  ws += (size_t)NTOK * 512 * 2;   // 64 MB: h_ln -> o -> h2
    bf16* big   = (bf16*)ws;                                  // 256 MB: qkv -> fc1 out
    const size_t needed = 6291456ull + 67108864ull + 268435456ull;
    if (ws_size < needed) return;

    // weight conversion
    f2b_kernel<<<768,  256, 0, stream>>>(qkv_w,  wQKV, 1536 * 512);
    f2b_kernel<<<256,  256, 0, stream>>>(proj_w, wPROJ, 512 * 512);
    f2b_kernel<<<1024, 256, 0, stream>>>(fc1_w,  wFC1, 2048 * 512);
    f2b_kernel<<<1024, 256, 0, stream>>>(fc2_w,  wFC2, 512 * 2048);

    // LN1: x -> hA (bf16)
    ln_kernel<<<NTOK / 4, 256, 0, stream>>>(x, ln_g, ln_b, hA);
    // qkv = hA @ qkv_w^T  -> big
    gemm256<0><<<dim3(6 * 256), 512, 0, stream>>>(
        hA, wQKV, NTOK, 1536, 512, 6, nullptr, nullptr, nullptr, big);
    // attention: big -> hA (o)
    attn_kernel<<<BQ, 256, 0, stream>>>(big, rpb, hA);
    // x1 = x + o @ proj_w^T + proj_b -> out (fp32)
    gemm256<1><<<dim3(2 * 256), 512, 0, stream>>>(
        hA, wPROJ, NTOK, 512, 512, 2, proj_b, x, out, nullptr);
    // LN2: out -> hA (h2)
    ln_kernel<<<NTOK / 4, 256, 0, stream>>>(out, ln_g, ln_b, hA);
    // g = gelu(h2 @ fc1_w^T + fc1_b) -> big (bf16)
    gemm256<2><<<dim3(8 * 256), 512, 0, stream>>>(
        hA, wFC1, NTOK, 2048, 512, 8, fc1_b, nullptr, nullptr, big);
    // out = x1 + g @ fc2_w^T + fc2_b (in-place residual read)
    gemm256<1><<<dim3(2 * 256), 512, 0, stream>>>(
        big, wFC2, NTOK, 512, 2048, 2, fc2_b, out, out, nullptr);
}

// Round 3
// 960.080 us; speedup vs baseline: 1.1497x; 1.1497x over previous
//
#include <hip/hip_runtime.h>
#include <hip/hip_bf16.h>
#include <math.h>

// Problem constants
#define BQ   16384        // windows
#define CH   512
#define NH   8
#define HID  2048
#define NTOK (BQ*4)       // 65536 rows

using bf16 = __hip_bfloat16;
typedef __bf16 bf16x8 __attribute__((ext_vector_type(8)));
typedef float  f32x4  __attribute__((ext_vector_type(4)));

#define FENCE() asm volatile("" ::: "memory")

__device__ __forceinline__ void gload16(const void* g, void* l) {
    __builtin_amdgcn_global_load_lds(
        (const __attribute__((address_space(1))) void*)g,
        (__attribute__((address_space(3))) void*)l, 16, 0, 0);
}

// ---------------- fp32 -> bf16 convert ----------------
__global__ __launch_bounds__(256) void f2b_kernel(const float* __restrict__ in,
                                                  bf16* __restrict__ out, int n) {
    int i = (blockIdx.x * 256 + threadIdx.x) * 4;
    if (i + 3 < n) {
        float4 v = *(const float4*)&in[i];
        __align__(8) bf16 t[4];
        t[0] = __float2bfloat16(v.x);
        t[1] = __float2bfloat16(v.y);
        t[2] = __float2bfloat16(v.z);
        t[3] = __float2bfloat16(v.w);
        *(uint2*)&out[i] = *(const uint2*)t;
    }
}

// ---------------- LayerNorm (fp32 in, bf16 out), one wave per row ----------------
__global__ __launch_bounds__(256) void ln_kernel(const float* __restrict__ x,
                                                 const float* __restrict__ g,
                                                 const float* __restrict__ b,
                                                 bf16* __restrict__ out) {
    int row  = blockIdx.x * 4 + (threadIdx.x >> 6);
    int lane = threadIdx.x & 63;
    const float* xr = x + (size_t)row * CH;
    int c0 = lane * 8;
    float4 v0 = *(const float4*)&xr[c0];
    float4 v1 = *(const float4*)&xr[c0 + 4];
    float s  = v0.x + v0.y + v0.z + v0.w + v1.x + v1.y + v1.z + v1.w;
    float sq = v0.x*v0.x + v0.y*v0.y + v0.z*v0.z + v0.w*v0.w
             + v1.x*v1.x + v1.y*v1.y + v1.z*v1.z + v1.w*v1.w;
#pragma unroll
    for (int off = 32; off >= 1; off >>= 1) {
        s  += __shfl_xor(s,  off, 64);
        sq += __shfl_xor(sq, off, 64);
    }
    float mu  = s * (1.0f / CH);
    float var = sq * (1.0f / CH) - mu * mu;
    float rs  = rsqrtf(var + 1e-5f);
    float4 g0 = *(const float4*)&g[c0];
    float4 g1 = *(const float4*)&g[c0 + 4];
    float4 b0 = *(const float4*)&b[c0];
    float4 b1 = *(const float4*)&b[c0 + 4];
    __align__(16) bf16 t[8];
    t[0] = __float2bfloat16((v0.x - mu) * rs * g0.x + b0.x);
    t[1] = __float2bfloat16((v0.y - mu) * rs * g0.y + b0.y);
    t[2] = __float2bfloat16((v0.z - mu) * rs * g0.z + b0.z);
    t[3] = __float2bfloat16((v0.w - mu) * rs * g0.w + b0.w);
    t[4] = __float2bfloat16((v1.x - mu) * rs * g1.x + b1.x);
    t[5] = __float2bfloat16((v1.y - mu) * rs * g1.y + b1.y);
    t[6] = __float2bfloat16((v1.z - mu) * rs * g1.z + b1.z);
    t[7] = __float2bfloat16((v1.w - mu) * rs * g1.w + b1.w);
    *(uint4*)&out[(size_t)row * CH + c0] = *(const uint4*)t;
}

// ---------------- GEMM 256x256 tile, BK=32 slices, ring-4 LDS, counted vmcnt ----
// C[M,N] = A[M,K] * B[N,K]^T
// EPI 0: outB = bf16(acc)                       (qkv)
// EPI 1: outF = acc + bias[col] + resid[idx]    (proj / fc2, fp32 out)
// EPI 2: outB = bf16(gelu(acc + bias[col]))     (fc1)
//
// LDS per slice-slot (32 KiB): A [256 rows][32k] (64B rows), then B same.
// XOR swizzle in 16B slots: kslot = kpart ^ ((row>>1)&3), realized by
// permuting the per-lane GLOBAL source address (gload_lds dest stays linear)
// and applying the same XOR on the frag ds_read_b128 addresses.
// -> staging: 16 fully-consumed 64B lines per load instr (coalesced)
// -> frag reads: rows 0..7 cover all 8 bank quads -> exactly 2-way (free).
// 4 slots = 128 KiB; prefetch depth 3 slices; steady-state vmcnt(12).
template<int EPI>
__global__ __launch_bounds__(512, 2)
void gemm256(const bf16* __restrict__ A, const bf16* __restrict__ Bw,
             int M, int N, int K, int nbx,
             const float* __restrict__ bias,
             const float* resid, float* outF, bf16* __restrict__ outB) {
    __shared__ __align__(16) char lds[131072];
    const int tid  = threadIdx.x;
    const int w    = tid >> 6;     // wave 0..7
    const int lane = tid & 63;

    // bijective XCD swizzle (gridDim.x % 8 == 0 for all our shapes)
    const int nb  = gridDim.x;
    const int id  = blockIdx.x;
    const int swz = (id & 7) * (nb >> 3) + (id >> 3);
    const int bx  = swz % nbx, by = swz / nbx;
    const int bm = by * 256, bn = bx * 256;
    const int wr = w >> 2;         // 0..1  (M half)
    const int wc = w & 3;          // 0..3  (N quarter)

    // staging source addresses (pre-swizzled global per-lane K-offset)
    const int rl  = lane >> 2;                               // row within 16-row chunk
    const int kpe = (((lane & 3) ^ ((lane >> 3) & 3))) * 8;  // permuted k-part (elems)
    const bf16* gA0 = A  + (size_t)(bm + w * 32 + rl) * K + kpe;
    const bf16* gA1 = gA0 + (size_t)16 * K;
    const bf16* gB0 = Bw + (size_t)(bn + w * 32 + rl) * K + kpe;
    const bf16* gB1 = gB0 + (size_t)16 * K;

    // fragment read offsets (bytes) within a slot; same XOR on the read side
    const int kslot = ((lane >> 4) ^ ((lane >> 1) & 3));
    const int aoff = (wr * 128 + (lane & 15)) * 64 + kslot * 16;
    const int boff = 16384 + (wc * 64 + (lane & 15)) * 64 + kslot * 16;

    f32x4 acc[8][4] = {};
    const int NS = K >> 5;         // K/32 slices (>= 16 for all our shapes)

    auto stage = [&](int ss) {
        char* base = (char*)lds + (ss & 3) * 32768;
        size_t ko = (size_t)ss * 32;
        gload16(gA0 + ko, base + w * 2048);
        gload16(gA1 + ko, base + w * 2048 + 1024);
        gload16(gB0 + ko, base + 16384 + w * 2048);
        gload16(gB1 + ko, base + 16384 + w * 2048 + 1024);
    };

    auto compute = [&](int slot) {
        const char* Ab = (const char*)lds + slot * 32768;
        bf16x8 av[8], bv[4];
#pragma unroll
        for (int n = 0; n < 4; ++n)
            bv[n] = *(const bf16x8*)(Ab + boff + n * 1024);
#pragma unroll
        for (int m = 0; m < 8; ++m)
            av[m] = *(const bf16x8*)(Ab + aoff + m * 1024);
        __builtin_amdgcn_s_setprio(1);
#pragma unroll
        for (int m = 0; m < 8; ++m)
#pragma unroll
            for (int n = 0; n < 4; ++n)
                acc[m][n] = __builtin_amdgcn_mfma_f32_16x16x32_bf16(av[m], bv[n], acc[m][n], 0, 0, 0);
        __builtin_amdgcn_s_setprio(0);
    };

    stage(0); stage(1); stage(2);              // depth-3 prologue (12 loads)
    for (int s = 0; s < NS - 3; ++s) {
        stage(s + 3);                          // 16 outstanding max
        asm volatile("s_waitcnt vmcnt(12)" ::: "memory");   // slice s landed
        __builtin_amdgcn_s_barrier();
        FENCE();
        compute(s & 3);
        FENCE();
        __builtin_amdgcn_s_barrier();          // compute(s) readers done before
    }                                          // stage(s+4) rewrites slot s&3
    // epilogue drain: 8 -> 4 -> 0
    asm volatile("s_waitcnt vmcnt(8)" ::: "memory");
    __builtin_amdgcn_s_barrier(); FENCE();
    compute((NS - 3) & 3);
    FENCE(); __builtin_amdgcn_s_barrier();
    asm volatile("s_waitcnt vmcnt(4)" ::: "memory");
    __builtin_amdgcn_s_barrier(); FENCE();
    compute((NS - 2) & 3);
    FENCE(); __builtin_amdgcn_s_barrier();
    asm volatile("s_waitcnt vmcnt(0)" ::: "memory");
    __builtin_amdgcn_s_barrier(); FENCE();
    compute((NS - 1) & 3);

    // epilogue: frag (m,n): row = wr*128 + m*16 + (lane>>4)*4 + r, col = wc*64 + n*16 + (lane&15)
    const int erow0 = bm + wr * 128 + (lane >> 4) * 4;
    const int ecol0 = bn + wc * 64 + (lane & 15);
#pragma unroll
    for (int m = 0; m < 8; ++m) {
#pragma unroll
        for (int n = 0; n < 4; ++n) {
            int col = ecol0 + n * 16;
#pragma unroll
            for (int r = 0; r < 4; ++r) {
                int row = erow0 + m * 16 + r;
                size_t idx = (size_t)row * N + col;
                float v = acc[m][n][r];
                if (EPI == 0) {
                    outB[idx] = __float2bfloat16(v);
                } else if (EPI == 1) {
                    outF[idx] = v + bias[col] + resid[idx];
                } else {
                    float t = v + bias[col];
                    float ge = 0.5f * t * (1.0f + erff(t * 0.70710678118654752f));
                    outB[idx] = __float2bfloat16(ge);
                }
            }
        }
    }
}

// ---------------- windowed attention: one block per window ----------------
__global__ __launch_bounds__(256)
void attn_kernel(const bf16* __restrict__ qkv, const float* __restrict__ rpb,
                 bf16* __restrict__ o) {
    __shared__ __align__(16) bf16 sT[4 * 1536];
    __shared__ float sS[NH][4][4];
    __shared__ float sP[NH][4][4];
    int b   = blockIdx.x;
    int tid = threadIdx.x;
    const bf16* src = qkv + (size_t)b * (4 * 1536);
#pragma unroll
    for (int it = 0; it < 3; ++it) {
        int e = (it * 256 + tid) * 8;
        *(uint4*)&sT[e] = *(const uint4*)&src[e];
    }
    __syncthreads();
    if (tid < 128) {
        int h = tid >> 4, i = (tid >> 2) & 3, j = tid & 3;
        const bf16* q = &sT[i * 1536 + h * 64];
        const bf16* k = &sT[j * 1536 + 512 + h * 64];
        float acc = 0.f;
#pragma unroll
        for (int d = 0; d < 64; ++d)
            acc += __bfloat162float(q[d]) * __bfloat162float(k[d]);
        int rel = (((i >> 1) - (j >> 1)) + 1) * 3 + (((i & 1) - (j & 1)) + 1);
        sS[h][i][j] = acc * 0.125f + rpb[rel * NH + h];
    }
    __syncthreads();
    if (tid < 32) {
        int h = tid >> 2, i = tid & 3;
        float s0 = sS[h][i][0], s1 = sS[h][i][1], s2 = sS[h][i][2], s3 = sS[h][i][3];
        float mx = fmaxf(fmaxf(s0, s1), fmaxf(s2, s3));
        float e0 = expf(s0 - mx), e1 = expf(s1 - mx), e2 = expf(s2 - mx), e3 = expf(s3 - mx);
        float inv = 1.f / (e0 + e1 + e2 + e3);
        sP[h][i][0] = e0 * inv; sP[h][i][1] = e1 * inv;
        sP[h][i][2] = e2 * inv; sP[h][i][3] = e3 * inv;
    }
    __syncthreads();
    {
        int h = tid >> 5, tl = tid & 31;
        int d = tl * 2;
        const bf16* v = &sT[1024 + h * 64 + d];
#pragma unroll
        for (int i = 0; i < 4; ++i) {
            float p0 = sP[h][i][0], p1 = sP[h][i][1], p2 = sP[h][i][2], p3 = sP[h][i][3];
            float o0 = p0 * __bfloat162float(v[0])        + p1 * __bfloat162float(v[1536])
                     + p2 * __bfloat162float(v[2 * 1536]) + p3 * __bfloat162float(v[3 * 1536]);
            float o1 = p0 * __bfloat162float(v[1])            + p1 * __bfloat162float(v[1536 + 1])
                     + p2 * __bfloat162float(v[2 * 1536 + 1]) + p3 * __bfloat162float(v[3 * 1536 + 1]);
            __hip_bfloat162 pr;
            pr.x = __float2bfloat16(o0);
            pr.y = __float2bfloat16(o1);
            *(__hip_bfloat162*)&o[(size_t)(b * 4 + i) * CH + h * 64 + d] = pr;
        }
    }
}

extern "C" void kernel_launch(void* const* d_in, const int* in_sizes, int n_in,
                              void* d_out, int out_size, void* d_ws, size_t ws_size,
                              hipStream_t stream) {
    const float* x      = (const float*)d_in[0];
    const float* ln_g   = (const float*)d_in[1];
    const float* ln_b   = (const float*)d_in[2];
    const float* qkv_w  = (const float*)d_in[3];
    const float* proj_w = (const float*)d_in[4];
    const float* proj_b = (const float*)d_in[5];
    const float* rpb    = (const float*)d_in[6];
    const float* fc1_w  = (const float*)d_in[7];
    const float* fc1_b  = (const float*)d_in[8];
    const float* fc2_w  = (const float*)d_in[9];
    const float* fc2_b  = (const float*)d_in[10];
    float* out = (float*)d_out;

    // workspace layout (16B aligned throughout)
    char* ws = (char*)d_ws;
    bf16* wQKV  = (bf16*)ws;  ws += (size_t)1536 * 512 * 2;   // 1.5 MB
    bf16* wPROJ = (bf16*)ws;  ws += (size_t)512  * 512 * 2;   // 0.5 MB
    bf16* wFC1  = (bf16*)ws;  ws += (size_t)2048 * 512 * 2;   // 2 MB
    bf16* wFC2  = (bf16*)ws;  ws += (size_t)512 * 2048 * 2;   // 2 MB
    bf16* hA    = (bf16*)ws;  ws += (size_t)NTOK * 512 * 2;   // 64 MB: h_ln -> o -> h2
    bf16* big   = (bf16*)ws;                                  // 256 MB: qkv -> fc1 out
    const size_t needed = 6291456ull + 67108864ull + 268435456ull;
    if (ws_size < needed) return;

    // weight conversion
    f2b_kernel<<<768,  256, 0, stream>>>(qkv_w,  wQKV, 1536 * 512);
    f2b_kernel<<<256,  256, 0, stream>>>(proj_w, wPROJ, 512 * 512);
    f2b_kernel<<<1024, 256, 0, stream>>>(fc1_w,  wFC1, 2048 * 512);
    f2b_kernel<<<1024, 256, 0, stream>>>(fc2_w,  wFC2, 512 * 2048);

    // LN1: x -> hA (bf16)
    ln_kernel<<<NTOK / 4, 256, 0, stream>>>(x, ln_g, ln_b, hA);
    // qkv = hA @ qkv_w^T  -> big
    gemm256<0><<<dim3(6 * 256), 512, 0, stream>>>(
        hA, wQKV, NTOK, 1536, 512, 6, nullptr, nullptr, nullptr, big);
    // attention: big -> hA (o)
    attn_kernel<<<BQ, 256, 0, stream>>>(big, rpb, hA);
    // x1 = x + o @ proj_w^T + proj_b -> out (fp32)
    gemm256<1><<<dim3(2 * 256), 512, 0, stream>>>(
        hA, wPROJ, NTOK, 512, 512, 2, proj_b, x, out, nullptr);
    // LN2: out -> hA (h2)
    ln_kernel<<<NTOK / 4, 256, 0, stream>>>(out, ln_g, ln_b, hA);
    // g = gelu(h2 @ fc1_w^T + fc1_b) -> big (bf16)
    gemm256<2><<<dim3(8 * 256), 512, 0, stream>>>(
        hA, wFC1, NTOK, 2048, 512, 8, fc1_b, nullptr, nullptr, big);
    // out = x1 + g @ fc2_w^T + fc2_b (in-place residual read)
    gemm256<1><<<dim3(2 * 256), 512, 0, stream>>>(
        big, wFC2, NTOK, 512, 2048, 2, fc2_b, out, out, nullptr);
}

// Round 4
// 912.225 us; speedup vs baseline: 1.2100x; 1.0525x over previous
//
#include <hip/hip_runtime.h>
#include <hip/hip_bf16.h>
#include <math.h>

// Problem constants
#define BQ   16384        // windows
#define CH   512
#define NH   8
#define HID  2048
#define NTOK (BQ*4)       // 65536 rows

using bf16 = __hip_bfloat16;
typedef __bf16 bf16x8 __attribute__((ext_vector_type(8)));
typedef float  f32x4  __attribute__((ext_vector_type(4)));

#define FENCE() asm volatile("" ::: "memory")

__device__ __forceinline__ void gload16(const void* g, void* l) {
    __builtin_amdgcn_global_load_lds(
        (const __attribute__((address_space(1))) void*)g,
        (__attribute__((address_space(3))) void*)l, 16, 0, 0);
}

// ---------------- fp32 -> bf16 convert ----------------
__global__ __launch_bounds__(256) void f2b_kernel(const float* __restrict__ in,
                                                  bf16* __restrict__ out, int n) {
    int i = (blockIdx.x * 256 + threadIdx.x) * 4;
    if (i + 3 < n) {
        float4 v = *(const float4*)&in[i];
        __align__(8) bf16 t[4];
        t[0] = __float2bfloat16(v.x);
        t[1] = __float2bfloat16(v.y);
        t[2] = __float2bfloat16(v.z);
        t[3] = __float2bfloat16(v.w);
        *(uint2*)&out[i] = *(const uint2*)t;
    }
}

// ---------------- LayerNorm (fp32 in, bf16 out), one wave per row ----------------
__global__ __launch_bounds__(256) void ln_kernel(const float* __restrict__ x,
                                                 const float* __restrict__ g,
                                                 const float* __restrict__ b,
                                                 bf16* __restrict__ out) {
    int row  = blockIdx.x * 4 + (threadIdx.x >> 6);
    int lane = threadIdx.x & 63;
    const float* xr = x + (size_t)row * CH;
    int c0 = lane * 8;
    float4 v0 = *(const float4*)&xr[c0];
    float4 v1 = *(const float4*)&xr[c0 + 4];
    float s  = v0.x + v0.y + v0.z + v0.w + v1.x + v1.y + v1.z + v1.w;
    float sq = v0.x*v0.x + v0.y*v0.y + v0.z*v0.z + v0.w*v0.w
             + v1.x*v1.x + v1.y*v1.y + v1.z*v1.z + v1.w*v1.w;
#pragma unroll
    for (int off = 32; off >= 1; off >>= 1) {
        s  += __shfl_xor(s,  off, 64);
        sq += __shfl_xor(sq, off, 64);
    }
    float mu  = s * (1.0f / CH);
    float var = sq * (1.0f / CH) - mu * mu;
    float rs  = rsqrtf(var + 1e-5f);
    float4 g0 = *(const float4*)&g[c0];
    float4 g1 = *(const float4*)&g[c0 + 4];
    float4 b0 = *(const float4*)&b[c0];
    float4 b1 = *(const float4*)&b[c0 + 4];
    __align__(16) bf16 t[8];
    t[0] = __float2bfloat16((v0.x - mu) * rs * g0.x + b0.x);
    t[1] = __float2bfloat16((v0.y - mu) * rs * g0.y + b0.y);
    t[2] = __float2bfloat16((v0.z - mu) * rs * g0.z + b0.z);
    t[3] = __float2bfloat16((v0.w - mu) * rs * g0.w + b0.w);
    t[4] = __float2bfloat16((v1.x - mu) * rs * g1.x + b1.x);
    t[5] = __float2bfloat16((v1.y - mu) * rs * g1.y + b1.y);
    t[6] = __float2bfloat16((v1.z - mu) * rs * g1.z + b1.z);
    t[7] = __float2bfloat16((v1.w - mu) * rs * g1.w + b1.w);
    *(uint4*)&out[(size_t)row * CH + c0] = *(const uint4*)t;
}

// ---------------- GEMM 256x256 tile, BK=32 slices, ring-4 LDS ------------------
// Software-pipelined register fragments: read slice s+1's frags between the
// barrier and slice s's MFMA cluster; ONE barrier per slice; counted vmcnt(8)
// in steady state (drain 4 -> 0 only in the peeled tail).
// C[M,N] = A[M,K] * B[N,K]^T
// EPI 0: outB = bf16(acc)                       (qkv)
// EPI 1: outF = acc + bias[col] + resid[idx]    (proj / fc2, fp32 out)
// EPI 2: outB = bf16(gelu_tanh(acc + bias))     (fc1)
template<int EPI>
__global__ __launch_bounds__(512, 2)
void gemm256(const bf16* __restrict__ A, const bf16* __restrict__ Bw,
             int M, int N, int K, int nbx,
             const float* __restrict__ bias,
             const float* resid, float* outF, bf16* __restrict__ outB) {
    __shared__ __align__(16) char lds[131072];
    const int tid  = threadIdx.x;
    const int w    = tid >> 6;     // wave 0..7
    const int lane = tid & 63;

    // bijective XCD swizzle (gridDim.x % 8 == 0 for all our shapes)
    const int nb  = gridDim.x;
    const int id  = blockIdx.x;
    const int swz = (id & 7) * (nb >> 3) + (id >> 3);
    const int bx  = swz % nbx, by = swz / nbx;
    const int bm = by * 256, bn = bx * 256;
    const int wr = w >> 2;         // 0..1  (M half)
    const int wc = w & 3;          // 0..3  (N quarter)

    // staging source addresses (pre-swizzled global per-lane K-offset)
    const int rl  = lane >> 2;                               // row within 16-row chunk
    const int kpe = (((lane & 3) ^ ((lane >> 3) & 3))) * 8;  // permuted k-part (elems)
    const bf16* gA0 = A  + (size_t)(bm + w * 32 + rl) * K + kpe;
    const bf16* gA1 = gA0 + (size_t)16 * K;
    const bf16* gB0 = Bw + (size_t)(bn + w * 32 + rl) * K + kpe;
    const bf16* gB1 = gB0 + (size_t)16 * K;

    // fragment read offsets (bytes) within a slot; same XOR on the read side
    const int kslot = ((lane >> 4) ^ ((lane >> 1) & 3));
    const int aoff = (wr * 128 + (lane & 15)) * 64 + kslot * 16;
    const int boff = 16384 + (wc * 64 + (lane & 15)) * 64 + kslot * 16;

    f32x4 acc[8][4] = {};
    const int NS = K >> 5;         // K/32 slices (16 or 64 here; even, >= 8)

    auto stage = [&](int ss) {
        char* base = (char*)lds + (ss & 3) * 32768;
        size_t ko = (size_t)ss * 32;
        gload16(gA0 + ko, base + w * 2048);
        gload16(gA1 + ko, base + w * 2048 + 1024);
        gload16(gB0 + ko, base + 16384 + w * 2048);
        gload16(gB1 + ko, base + 16384 + w * 2048 + 1024);
    };

    bf16x8 avA[8], bvA[4], avB[8], bvB[4];

#define READF(AV, BV, SLOT) do {                                            \
    const char* _b = (const char*)lds + (size_t)(SLOT) * 32768;             \
    _Pragma("unroll") for (int _n = 0; _n < 4; ++_n)                        \
        BV[_n] = *(const bf16x8*)(_b + boff + _n * 1024);                   \
    _Pragma("unroll") for (int _m = 0; _m < 8; ++_m)                        \
        AV[_m] = *(const bf16x8*)(_b + aoff + _m * 1024);                   \
} while (0)

#define MFMAC(AV, BV) do {                                                  \
    __builtin_amdgcn_s_setprio(1);                                          \
    _Pragma("unroll") for (int _m = 0; _m < 8; ++_m)                        \
    _Pragma("unroll") for (int _n = 0; _n < 4; ++_n)                        \
        acc[_m][_n] = __builtin_amdgcn_mfma_f32_16x16x32_bf16(              \
            AV[_m], BV[_n], acc[_m][_n], 0, 0, 0);                          \
    __builtin_amdgcn_s_setprio(0);                                          \
} while (0)

    // prologue: depth-3 ring fill, load slice 0 frags into bank A
    stage(0); stage(1); stage(2);
    asm volatile("s_waitcnt vmcnt(8)" ::: "memory");   // slice 0 landed
    __builtin_amdgcn_s_barrier();
    FENCE();
    READF(avA, bvA, 0);

    // main loop: pairs (even: A->compute, B->load) / (odd: B->compute, A->load)
    for (int s = 0; s < NS - 2; s += 2) {
        // even body: mfma slice s (bank A), read slice s+1 (bank B)
        stage(s + 3);
        asm volatile("s_waitcnt vmcnt(8)" ::: "memory");   // slice s+1 landed
        __builtin_amdgcn_s_barrier();
        FENCE();
        READF(avB, bvB, (s + 1) & 3);
        MFMAC(avA, bvA);
        // odd body: mfma slice s+1 (bank B), read slice s+2 (bank A)
        if (s + 4 < NS) {
            stage(s + 4);
            asm volatile("s_waitcnt vmcnt(8)" ::: "memory");
        } else {
            asm volatile("s_waitcnt vmcnt(4)" ::: "memory");
        }
        __builtin_amdgcn_s_barrier();
        FENCE();
        READF(avA, bvA, (s + 2) & 3);
        MFMAC(avB, bvB);
    }
    // tail: bank A holds slice NS-2; read slice NS-1, compute both
    asm volatile("s_waitcnt vmcnt(0)" ::: "memory");
    __builtin_amdgcn_s_barrier();
    FENCE();
    READF(avB, bvB, (NS - 1) & 3);
    MFMAC(avA, bvA);
    MFMAC(avB, bvB);
#undef READF
#undef MFMAC

    // epilogue: frag (m,n): row = wr*128 + m*16 + (lane>>4)*4 + r, col = wc*64 + n*16 + (lane&15)
    const int erow0 = bm + wr * 128 + (lane >> 4) * 4;
    const int ecol0 = bn + wc * 64 + (lane & 15);
#pragma unroll
    for (int m = 0; m < 8; ++m) {
#pragma unroll
        for (int n = 0; n < 4; ++n) {
            int col = ecol0 + n * 16;
#pragma unroll
            for (int r = 0; r < 4; ++r) {
                int row = erow0 + m * 16 + r;
                size_t idx = (size_t)row * N + col;
                float v = acc[m][n][r];
                if (EPI == 0) {
                    outB[idx] = __float2bfloat16(v);
                } else if (EPI == 1) {
                    outF[idx] = v + bias[col] + resid[idx];
                } else {
                    // tanh-form GELU (|err| vs exact erf-GELU ~3e-4 << bf16 ulp)
                    float t = v + bias[col];
                    float u = 0.7978845608f * t * (1.0f + 0.044715f * t * t);
                    float e = __expf(2.0f * u);
                    float th = 1.0f - 2.0f / (e + 1.0f);   // inf-safe: e=inf -> th=1
                    outB[idx] = __float2bfloat16(0.5f * t * (1.0f + th));
                }
            }
        }
    }
}

// ---------------- windowed attention: one block per window ----------------
__global__ __launch_bounds__(256)
void attn_kernel(const bf16* __restrict__ qkv, const float* __restrict__ rpb,
                 bf16* __restrict__ o) {
    __shared__ __align__(16) bf16 sT[4 * 1536];
    __shared__ float sS[NH][4][4];
    __shared__ float sP[NH][4][4];
    int b   = blockIdx.x;
    int tid = threadIdx.x;
    const bf16* src = qkv + (size_t)b * (4 * 1536);
#pragma unroll
    for (int it = 0; it < 3; ++it) {
        int e = (it * 256 + tid) * 8;
        *(uint4*)&sT[e] = *(const uint4*)&src[e];
    }
    __syncthreads();
    if (tid < 128) {
        int h = tid >> 4, i = (tid >> 2) & 3, j = tid & 3;
        const bf16* q = &sT[i * 1536 + h * 64];
        const bf16* k = &sT[j * 1536 + 512 + h * 64];
        float acc = 0.f;
#pragma unroll
        for (int d = 0; d < 64; ++d)
            acc += __bfloat162float(q[d]) * __bfloat162float(k[d]);
        int rel = (((i >> 1) - (j >> 1)) + 1) * 3 + (((i & 1) - (j & 1)) + 1);
        sS[h][i][j] = acc * 0.125f + rpb[rel * NH + h];
    }
    __syncthreads();
    if (tid < 32) {
        int h = tid >> 2, i = tid & 3;
        float s0 = sS[h][i][0], s1 = sS[h][i][1], s2 = sS[h][i][2], s3 = sS[h][i][3];
        float mx = fmaxf(fmaxf(s0, s1), fmaxf(s2, s3));
        float e0 = expf(s0 - mx), e1 = expf(s1 - mx), e2 = expf(s2 - mx), e3 = expf(s3 - mx);
        float inv = 1.f / (e0 + e1 + e2 + e3);
        sP[h][i][0] = e0 * inv; sP[h][i][1] = e1 * inv;
        sP[h][i][2] = e2 * inv; sP[h][i][3] = e3 * inv;
    }
    __syncthreads();
    {
        int h = tid >> 5, tl = tid & 31;
        int d = tl * 2;
        const bf16* v = &sT[1024 + h * 64 + d];
#pragma unroll
        for (int i = 0; i < 4; ++i) {
            float p0 = sP[h][i][0], p1 = sP[h][i][1], p2 = sP[h][i][2], p3 = sP[h][i][3];
            float o0 = p0 * __bfloat162float(v[0])        + p1 * __bfloat162float(v[1536])
                     + p2 * __bfloat162float(v[2 * 1536]) + p3 * __bfloat162float(v[3 * 1536]);
            float o1 = p0 * __bfloat162float(v[1])            + p1 * __bfloat162float(v[1536 + 1])
                     + p2 * __bfloat162float(v[2 * 1536 + 1]) + p3 * __bfloat162float(v[3 * 1536 + 1]);
            __hip_bfloat162 pr;
            pr.x = __float2bfloat16(o0);
            pr.y = __float2bfloat16(o1);
            *(__hip_bfloat162*)&o[(size_t)(b * 4 + i) * CH + h * 64 + d] = pr;
        }
    }
}

extern "C" void kernel_launch(void* const* d_in, const int* in_sizes, int n_in,
                              void* d_out, int out_size, void* d_ws, size_t ws_size,
                              hipStream_t stream) {
    const float* x      = (const float*)d_in[0];
    const float* ln_g   = (const float*)d_in[1];
    const float* ln_b   = (const float*)d_in[2];
    const float* qkv_w  = (const float*)d_in[3];
    const float* proj_w = (const float*)d_in[4];
    const float* proj_b = (const float*)d_in[5];
    const float* rpb    = (const float*)d_in[6];
    const float* fc1_w  = (const float*)d_in[7];
    const float* fc1_b  = (const float*)d_in[8];
    const float* fc2_w  = (const float*)d_in[9];
    const float* fc2_b  = (const float*)d_in[10];
    float* out = (float*)d_out;

    // workspace layout (16B aligned throughout)
    char* ws = (char*)d_ws;
    bf16* wQKV  = (bf16*)ws;  ws += (size_t)1536 * 512 * 2;   // 1.5 MB
    bf16* wPROJ = (bf16*)ws;  ws += (size_t)512  * 512 * 2;   // 0.5 MB
    bf16* wFC1  = (bf16*)ws;  ws += (size_t)2048 * 512 * 2;   // 2 MB
    bf16* wFC2  = (bf16*)ws;  ws += (size_t)512 * 2048 * 2;   // 2 MB
    bf16* hA    = (bf16*)ws;  ws += (size_t)NTOK * 512 * 2;   // 64 MB: h_ln -> o -> h2
    bf16* big   = (bf16*)ws;                                  // 256 MB: qkv -> fc1 out
    const size_t needed = 6291456ull + 67108864ull + 268435456ull;
    if (ws_size < needed) return;

    // weight conversion
    f2b_kernel<<<768,  256, 0, stream>>>(qkv_w,  wQKV, 1536 * 512);
    f2b_kernel<<<256,  256, 0, stream>>>(proj_w, wPROJ, 512 * 512);
    f2b_kernel<<<1024, 256, 0, stream>>>(fc1_w,  wFC1, 2048 * 512);
    f2b_kernel<<<1024, 256, 0, stream>>>(fc2_w,  wFC2, 512 * 2048);

    // LN1: x -> hA (bf16)
    ln_kernel<<<NTOK / 4, 256, 0, stream>>>(x, ln_g, ln_b, hA);
    // qkv = hA @ qkv_w^T  -> big
    gemm256<0><<<dim3(6 * 256), 512, 0, stream>>>(
        hA, wQKV, NTOK, 1536, 512, 6, nullptr, nullptr, nullptr, big);
    // attention: big -> hA (o)
    attn_kernel<<<BQ, 256, 0, stream>>>(big, rpb, hA);
    // x1 = x + o @ proj_w^T + proj_b -> out (fp32)
    gemm256<1><<<dim3(2 * 256), 512, 0, stream>>>(
        hA, wPROJ, NTOK, 512, 512, 2, proj_b, x, out, nullptr);
    // LN2: out -> hA (h2)
    ln_kernel<<<NTOK / 4, 256, 0, stream>>>(out, ln_g, ln_b, hA);
    // g = gelu(h2 @ fc1_w^T + fc1_b) -> big (bf16)
    gemm256<2><<<dim3(8 * 256), 512, 0, stream>>>(
        hA, wFC1, NTOK, 2048, 512, 8, fc1_b, nullptr, nullptr, big);
    // out = x1 + g @ fc2_w^T + fc2_b (in-place residual read)
    gemm256<1><<<dim3(2 * 256), 512, 0, stream>>>(
        big, wFC2, NTOK, 512, 2048, 2, fc2_b, out, out, nullptr);
}